// Round 1
// 200.920 us; speedup vs baseline: 1.0722x; 1.0722x over previous
//
#include <hip/hip_runtime.h>

#define HH 256
#define WW 256
#define HWPX 65536
#define BB 8
#define KK 21
#define CC 32

typedef _Float16 half2v __attribute__((ext_vector_type(2)));
union F4H { float4 f4; half2v h[4]; };

// ---------------- kernel 1 (fused): T + |q|^2 + planar f16 pack, 1 px/thread ----------------
// 1 px/thread -> 2048 blocks -> 8 blocks/CU (100% occupancy cap; was 512 blocks = 25% cap).
// Scalar 4B loads stay fully coalesced (64 lanes x 4B = 4 full lines/instr); kernel is
// BW-bound (187 MB), instruction count is irrelevant.
// fpk layout: plane j (8 channels), plane stride BB*HWPX float4s; within plane
// [global pixel idx] -> 16 B, lane-contiguous.
__global__ __launch_bounds__(256) void prep(const float* __restrict__ cls,
                                            const float* __restrict__ feat,
                                            float4* __restrict__ fpk,
                                            float2* __restrict__ TN) {
    const int tid = blockIdx.x * 256 + threadIdx.x;   // 0..524287 (global pixel idx b*HWPX+p)
    const int b = tid >> 16;
    const int p = tid & (HWPX - 1);

    // T = sum_k S
    const float* cbase = cls + (size_t)b * KK * HWPX + p;
    float T = 0.f;
#pragma unroll
    for (int k = 0; k < KK; ++k) T += cbase[(size_t)k * HWPX];

    const float* src = feat + (size_t)b * CC * HWPX + p;
    float nq = 0.f;
#pragma unroll
    for (int j = 0; j < 4; ++j) {
        F4H u;
#pragma unroll
        for (int k = 0; k < 4; ++k) {
            float a  = src[(size_t)(j * 8 + 2 * k) * HWPX];
            float b2 = src[(size_t)(j * 8 + 2 * k + 1) * HWPX];
            u.h[k] = __builtin_bit_cast(half2v, __builtin_amdgcn_cvt_pkrtz(a, b2));
            nq = __builtin_amdgcn_fdot2(u.h[k], u.h[k], nq, false);
        }
        fpk[(size_t)j * (BB * HWPX) + tid] = u.f4;    // 16 B/px/plane, lane-contiguous
    }
    TN[tid] = make_float2(T, nq);
}

// ---------------- kernel 2 (hot): planar f16 affinity, 4 stacked px/thread ----------------
// w(p,q) = exp(-off^2/16 - (|p|^2+|q|^2-2 p.q)); acc telescopes, w = exp2(2*log2e*acc).
// dyi loop split across 2 blocks (chunk 0: dyi 0..5, chunk 1: 6..11) -> grid 1024
// (4 blocks/CU, 50% occupancy cap; was 512 = 25% cap). Each chunk writes its own
// V/deg buffer (deterministic, no atomics); reduce_bj sums the two halves.
// 4-px stacking kept: per-column neighbor load (72 B) still serves 4 pixels (L1 budget).
__global__ __launch_bounds__(256) void affinity4(const float4* __restrict__ fpk,
                                                 const float2* __restrict__ TN,
                                                 float* __restrict__ V,
                                                 float* __restrict__ deg) {
    // XCD swizzle: L%8 = batch so each XCD's round-robin share is one batch (~4.7 MB, L2-resident)
    const int L  = blockIdx.x;            // 0..1023
    const int b  = L & 7;
    const int t  = L >> 3;                // 0..127
    const int by = t & 15;
    const int bx = (t >> 4) & 3;          // 0..3
    const int half = t >> 6;              // 0..1 : dyi chunk
    const int lane = threadIdx.x & 63;
    const int wid  = threadIdx.x >> 6;
    const int gx  = bx * 64 + lane;
    const int gy0 = by * 16 + wid * 4;    // owns rows gy0..gy0+3

    const size_t bofs = (size_t)b * HWPX;
    const float4* fb0 = fpk + bofs;
    const float4* fb1 = fpk + (size_t)1 * BB * HWPX + bofs;
    const float4* fb2 = fpk + (size_t)2 * BB * HWPX + bofs;
    const float4* fb3 = fpk + (size_t)3 * BB * HWPX + bofs;
    const float2* tnb = TN + bofs;

    F4H fp[4][4];
    float np_[4];
#pragma unroll
    for (int py = 0; py < 4; ++py) {
        const int pp = ((gy0 + py) << 8) | gx;
        fp[py][0].f4 = fb0[pp];
        fp[py][1].f4 = fb1[pp];
        fp[py][2].f4 = fb2[pp];
        fp[py][3].f4 = fb3[pp];
        np_[py] = tnb[pp].y;
    }

    float degacc[4] = {0.f, 0.f, 0.f, 0.f};
    float vacc[4]   = {0.f, 0.f, 0.f, 0.f};

    const int dy_lo = half * 6;
    const int dy_hi = dy_lo + 6;

#pragma unroll 1   // runtime row loop: caps load-hoisting window (round-3 spill lesson)
    for (int dyi = dy_lo; dyi < dy_hi; ++dyi) {
        const int ny = gy0 + dyi - 4;               // neighbor row, same for all py
        if ((unsigned)ny >= HH) continue;           // uniform: OOB row contributes 0
        const int rowq = ny << 8;

        int dy2[4];
        float base[4];
#pragma unroll
        for (int py = 0; py < 4; ++py) {
            const int d = dyi - 4 - py;             // uniform
            dy2[py] = d * d;
            base[py] = fmaf(-0.03125f, (float)dy2[py], -0.5f * np_[py]);
        }
        const int mind = min(min(dy2[0], dy2[1]), min(dy2[2], dy2[3]));

#pragma unroll 3
        for (int dxi = 0; dxi < 9; ++dxi) {
            const int dx = dxi - 4;                 // uniform
            const int dx2 = dx * dx;
            if (mind + dx2 >= 25) continue;         // uniform: no py uses this column

            const int gx2 = gx + dx;
            const bool vx = (unsigned)gx2 < WW;     // per-lane x bound
            const int q = rowq | min(max(gx2, 0), WW - 1);

            F4H nb0, nb1, nb2, nb3;
            nb0.f4 = fb0[q];
            nb1.f4 = fb1[q];
            nb2.f4 = fb2[q];
            nb3.f4 = fb3[q];
            const float2 tq = tnb[q];
            const float cdx = (float)dx2 * -0.03125f;

#pragma unroll
            for (int py = 0; py < 4; ++py) {
                if (dy2[py] + dx2 < 25) {           // uniform circle test
                    float acc = fmaf(-0.5f, tq.y, base[py] + cdx);
#pragma unroll
                    for (int k = 0; k < 4; ++k) {
                        acc = __builtin_amdgcn_fdot2(fp[py][0].h[k], nb0.h[k], acc, false);
                        acc = __builtin_amdgcn_fdot2(fp[py][1].h[k], nb1.h[k], acc, false);
                        acc = __builtin_amdgcn_fdot2(fp[py][2].h[k], nb2.h[k], acc, false);
                        acc = __builtin_amdgcn_fdot2(fp[py][3].h[k], nb3.h[k], acc, false);
                    }
                    float w = __builtin_exp2f(acc * 2.8853900817779268f);  // exp(2*acc)
                    w = vx ? w : 0.f;
                    degacc[py] += w;
                    vacc[py] = fmaf(w, tq.x, vacc[py]);
                }
            }
        }
    }

    float* Vh = V   + (size_t)half * (BB * HWPX);
    float* Dh = deg + (size_t)half * (BB * HWPX);
#pragma unroll
    for (int py = 0; py < 4; ++py) {
        const size_t o = bofs + ((size_t)(gy0 + py) << 8) + gx;
        Vh[o] = vacc[py];
        Dh[o] = degacc[py];
    }
}

// ---------------- kernel 3: per-(b,j) numer/denom, single pass, 4 px/thread ----------------
__global__ __launch_bounds__(256) void reduce_bj(const float* __restrict__ cls,
                                                 const float* __restrict__ V,
                                                 const float* __restrict__ deg,
                                                 float* __restrict__ numer,
                                                 float* __restrict__ denom) {
    __shared__ float smN[4][22], smD[4][22];
    const int b = blockIdx.y;
    const int p4 = (blockIdx.x * 256 + threadIdx.x) * 4;   // grid.x=64 covers HWPX

    const float* clsb = cls + (size_t)b * KK * HWPX;
    const float* Vb = V + (size_t)b * HWPX;
    const float* Db = deg + (size_t)b * HWPX;
    const float4 va = *(const float4*)(Vb + p4);
    const float4 vb = *(const float4*)(Vb + (size_t)BB * HWPX + p4);
    const float4 da = *(const float4*)(Db + p4);
    const float4 db = *(const float4*)(Db + (size_t)BB * HWPX + p4);
    const float4 v4 = make_float4(va.x + vb.x, va.y + vb.y, va.z + vb.z, va.w + vb.w);
    const float4 d4 = make_float4(da.x + db.x, da.y + db.y, da.z + db.z, da.w + db.w);

    float accN[KK], accD[KK];
#pragma unroll
    for (int j = 0; j < KK; ++j) {
        float4 s4 = *(const float4*)(clsb + (size_t)j * HWPX + p4);
        float n = s4.x * v4.x;  n = fmaf(s4.y, v4.y, n);
        n = fmaf(s4.z, v4.z, n); n = fmaf(s4.w, v4.w, n);
        float d = s4.x * d4.x;  d = fmaf(s4.y, d4.y, d);
        d = fmaf(s4.z, d4.z, d); d = fmaf(s4.w, d4.w, d);
        accN[j] = n; accD[j] = d;
    }

    const int wid = threadIdx.x >> 6;
#pragma unroll
    for (int j = 0; j < KK; ++j) {
        float n = accN[j], d = accD[j];
#pragma unroll
        for (int off = 32; off > 0; off >>= 1) {
            n += __shfl_down(n, off);
            d += __shfl_down(d, off);
        }
        if ((threadIdx.x & 63) == 0) { smN[wid][j] = n; smD[wid][j] = d; }
    }
    __syncthreads();
    if (threadIdx.x < 2 * KK) {
        int half = threadIdx.x / KK;
        int j = threadIdx.x - half * KK;
        float acc = half ? (smD[0][j] + smD[1][j] + smD[2][j] + smD[3][j])
                         : (smN[0][j] + smN[1][j] + smN[2][j] + smN[3][j]);
        float* dst = half ? denom : numer;
        atomicAdd(&dst[b * KK + j], acc);
    }
}

// ---------------- kernel 4: out = sum_{b,j} numer/denom ----------------
__global__ __launch_bounds__(256) void finalize(const float* __restrict__ numer,
                                                const float* __restrict__ denom,
                                                float* __restrict__ out) {
    __shared__ float sm[4];
    int i = threadIdx.x;
    float r = 0.f;
    if (i < BB * KK) r = numer[i] / denom[i];
#pragma unroll
    for (int off = 32; off > 0; off >>= 1) r += __shfl_down(r, off);
    if ((i & 63) == 0) sm[i >> 6] = r;
    __syncthreads();
    if (i == 0) out[0] = sm[0] + sm[1] + sm[2] + sm[3];
}

extern "C" void kernel_launch(void* const* d_in, const int* in_sizes, int n_in,
                              void* d_out, int out_size, void* d_ws, size_t ws_size,
                              hipStream_t stream) {
    const float* cls  = (const float*)d_in[0];  // [B,K,H,W]
    const float* feat = (const float*)d_in[1];  // [B,C,H,W]
    float* out = (float*)d_out;

    const size_t BHW = (size_t)BB * HWPX;
    // fpk (33.5 MB) | TN (4.2 MB) | V[2] | deg[2] | numer | denom   (~46.4 MB)
    float4* fpk  = (float4*)d_ws;
    float2* TN   = (float2*)((char*)d_ws + BHW * 64);
    float*  V    = (float*)((char*)TN + BHW * 8);        // 2*BHW floats (two dyi-chunks)
    float*  deg  = V + 2 * BHW;                           // 2*BHW floats
    float*  numer = deg + 2 * BHW;
    float*  denom = numer + BB * KK;

    (void)hipMemsetAsync(numer, 0, 2 * BB * KK * sizeof(float), stream);
    prep<<<dim3((BB * HWPX) / 256), dim3(256), 0, stream>>>(cls, feat, fpk, TN);
    affinity4<<<dim3(1024), dim3(256), 0, stream>>>(fpk, TN, V, deg);
    reduce_bj<<<dim3(HWPX / 1024, BB), dim3(256), 0, stream>>>(cls, V, deg, numer, denom);
    finalize<<<dim3(1), dim3(256), 0, stream>>>(numer, denom, out);
}